// Round 5
// baseline (1283.119 us; speedup 1.0000x reference)
//
#include <hip/hip_runtime.h>

#define NN  50000   // nodes
#define KIN 2000    // in features
#define DD  64      // latent dim
#define NE  800000  // edges

using f4 = __attribute__((ext_vector_type(4))) float;

// Zero the two atomic accumulators (x_latent in d_out, z in ws).
__global__ __launch_bounds__(256) void zero_two(float* __restrict__ a,
                                                float* __restrict__ b, int n4) {
  f4 zv = {0.f, 0.f, 0.f, 0.f};
  for (int i = blockIdx.x * blockDim.x + threadIdx.x; i < n4;
       i += gridDim.x * blockDim.x) {
    ((f4*)a)[i] = zv;
    ((f4*)b)[i] = zv;
  }
}

// h[N,64] = feat[N,2000] @ w_enc[2000,64]
// BM=128 rows, BN=64 (all cols), BK=16. 256 threads, per-thread 8x4 micro-tile.
__global__ __launch_bounds__(256) void gemm_enc(const float* __restrict__ feat,
                                                const float* __restrict__ w,
                                                float* __restrict__ h) {
  __shared__ float sA[16][132];  // feat tile transposed [k][row], +4 pad
  __shared__ float sB[16][64];   // w tile [k][col]
  const int tid  = threadIdx.x;
  const int brow = blockIdx.x * 128;
  const int tr = tid & 15;        // row group: rows tr*8 .. tr*8+7
  const int tc = tid >> 4;        // col group: cols tc*4 .. tc*4+3
  // staging indices: feat tile 128x16 -> 2 float4/thread; w tile 16x64 -> 1 float4
  const int lrow = tid >> 2;            // 0..63
  const int lk   = (tid & 3) * 4;       // 0,4,8,12
  const int wk   = tid >> 4;            // 0..15
  const int wc   = (tid & 15) * 4;      // 0..60
  const int row0 = brow + lrow;
  const int row1 = row0 + 64;

  float acc[8][4] = {};
  for (int k0 = 0; k0 < KIN; k0 += 16) {
    f4 a0 = {0,0,0,0}, a1 = {0,0,0,0};
    if (row0 < NN) a0 = *(const f4*)(feat + (size_t)row0 * KIN + k0 + lk);
    if (row1 < NN) a1 = *(const f4*)(feat + (size_t)row1 * KIN + k0 + lk);
    f4 bv = *(const f4*)(w + (size_t)(k0 + wk) * DD + wc);
    __syncthreads();  // previous tile fully consumed
    sA[lk+0][lrow] = a0[0]; sA[lk+1][lrow] = a0[1];
    sA[lk+2][lrow] = a0[2]; sA[lk+3][lrow] = a0[3];
    sA[lk+0][lrow+64] = a1[0]; sA[lk+1][lrow+64] = a1[1];
    sA[lk+2][lrow+64] = a1[2]; sA[lk+3][lrow+64] = a1[3];
    *(f4*)&sB[wk][wc] = bv;
    __syncthreads();
#pragma unroll
    for (int k = 0; k < 16; ++k) {
      f4 av0 = *(const f4*)&sA[k][tr*8];
      f4 av1 = *(const f4*)&sA[k][tr*8+4];
      f4 b   = *(const f4*)&sB[k][tc*4];
#pragma unroll
      for (int i = 0; i < 4; ++i)
#pragma unroll
        for (int j = 0; j < 4; ++j) {
          acc[i][j]   += av0[i] * b[j];
          acc[i+4][j] += av1[i] * b[j];
        }
    }
  }
#pragma unroll
  for (int i = 0; i < 8; ++i) {
    int row = brow + tr*8 + i;
    if (row < NN) {
      f4 v = {acc[i][0], acc[i][1], acc[i][2], acc[i][3]};
      *(f4*)(h + (size_t)row * DD + tc*4) = v;
    }
  }
}

// y[dst,:] += val * x[src,:]  (64-wide rows), one wave per edge.
__global__ __launch_bounds__(256) void spmm64(const int* __restrict__ rows,
                                              const int* __restrict__ cols,
                                              const float* __restrict__ vals,
                                              const float* __restrict__ x,
                                              float* __restrict__ y) {
  const int e    = blockIdx.x * 4 + (threadIdx.x >> 6);
  const int lane = threadIdx.x & 63;
  const int dst = rows[e];
  const int src = cols[e];
  const float v = vals[e];
  atomicAdd(y + (size_t)dst * DD + lane, v * x[(size_t)src * DD + lane]);
}

// out[N,2000] = z[N,64] @ w_dec[64,2000]; K=64 staged fully, 64x64 tiles.
__global__ __launch_bounds__(256) void gemm_dec(const float* __restrict__ z,
                                                const float* __restrict__ w,
                                                float* __restrict__ out) {
  __shared__ float sA[64][68];  // z tile transposed [k][row], +4 pad
  __shared__ float sB[64][64];  // w tile [k][col]
  const int tid  = threadIdx.x;
  const int brow = blockIdx.x * 64;
  const int bcol = blockIdx.y * 64;
  {
    const int zr   = tid >> 2;
    const int zseg = (tid & 3) * 16;
    const int zrow = brow + zr;
#pragma unroll
    for (int i = 0; i < 4; ++i) {
      f4 v = {0,0,0,0};
      if (zrow < NN) v = *(const f4*)(z + (size_t)zrow * DD + zseg + 4*i);
      sA[zseg + 4*i + 0][zr] = v[0];
      sA[zseg + 4*i + 1][zr] = v[1];
      sA[zseg + 4*i + 2][zr] = v[2];
      sA[zseg + 4*i + 3][zr] = v[3];
    }
    const int wk   = tid >> 2;
    const int wseg = (tid & 3) * 16;
#pragma unroll
    for (int i = 0; i < 4; ++i) {
      int col = bcol + wseg + 4*i;
      f4 v = {0,0,0,0};
      if (col < KIN) v = *(const f4*)(w + (size_t)wk * KIN + col);
      *(f4*)&sB[wk][wseg + 4*i] = v;
    }
  }
  __syncthreads();
  const int tr = tid & 15;
  const int tc = tid >> 4;
  float acc[4][4] = {};
#pragma unroll 8
  for (int k = 0; k < 64; ++k) {
    f4 a = *(const f4*)&sA[k][tr*4];
    f4 b = *(const f4*)&sB[k][tc*4];
#pragma unroll
    for (int i = 0; i < 4; ++i)
#pragma unroll
      for (int j = 0; j < 4; ++j)
        acc[i][j] += a[i] * b[j];
  }
#pragma unroll
  for (int i = 0; i < 4; ++i) {
    int row = brow + tr*4 + i;
    int col = bcol + tc*4;
    if (row < NN && col < KIN) {
      f4 v = {acc[i][0], acc[i][1], acc[i][2], acc[i][3]};
      *(f4*)(out + (size_t)row * KIN + col) = v;
    }
  }
}

extern "C" void kernel_launch(void* const* d_in, const int* in_sizes, int n_in,
                              void* d_out, int out_size, void* d_ws, size_t ws_size,
                              hipStream_t stream) {
  const float* feat     = (const float*)d_in[0];
  const int*   adj_rows = (const int*)d_in[1];
  const int*   adj_cols = (const int*)d_in[2];
  const float* adj_vals = (const float*)d_in[3];
  const float* w_enc    = (const float*)d_in[4];
  const float* w_dec    = (const float*)d_in[5];

  float* x_latent = (float*)d_out;                       // [N,64]
  float* x_recon  = (float*)d_out + (size_t)NN * DD;     // [N,2000]
  float* h        = (float*)d_ws;                        // [N,64] scratch
  float* zb       = (float*)d_ws + (size_t)NN * DD;      // [N,64] scratch

  // 1. zero atomic accumulators
  zero_two<<<2048, 256, 0, stream>>>(x_latent, zb, NN * DD / 4);
  // 2. h = feat @ W_enc
  gemm_enc<<<(NN + 127) / 128, 256, 0, stream>>>(feat, w_enc, h);
  // 3. x_latent = A @ h
  spmm64<<<NE / 4, 256, 0, stream>>>(adj_rows, adj_cols, adj_vals, h, x_latent);
  // 4. z = A @ x_latent   (associativity: A @ (X @ W) == (A @ X) @ W)
  spmm64<<<NE / 4, 256, 0, stream>>>(adj_rows, adj_cols, adj_vals, x_latent, zb);
  // 5. x_recon = z @ W_dec
  gemm_dec<<<dim3((NN + 63) / 64, (KIN + 63) / 64), 256, 0, stream>>>(zb, w_dec, x_recon);
}